// Round 1
// 155.885 us; speedup vs baseline: 1.9616x; 1.9616x over previous
//
#include <hip/hip_runtime.h>

typedef _Float16 half8 __attribute__((ext_vector_type(8)));
typedef float f32x4 __attribute__((ext_vector_type(4)));

#define MFMA16(a, b, c) __builtin_amdgcn_mfma_f32_16x16x32_f16((a), (b), (c), 0, 0, 0)

static __device__ __forceinline__ unsigned short hfbits(float f) {
  return __builtin_bit_cast(unsigned short, (_Float16)f);
}

// async global->LDS, 16B per lane; LDS dest = uniform base + lane*16
static __device__ __forceinline__ void gl16(const ushort* g, ushort* l) {
  __builtin_amdgcn_global_load_lds(
      (const __attribute__((address_space(1))) unsigned int*)g,
      (__attribute__((address_space(3))) unsigned int*)l, 16, 0, 0);
}

// ---------------------------------------------------------------------------
// Kernel 1: W [1024][3072] f32  ->  Wt [3072][1024] fp16 (transposed + cast)
// ---------------------------------------------------------------------------
__global__ __launch_bounds__(256) void k_wt(const float* __restrict__ W,
                                            ushort* __restrict__ wt) {
  __shared__ ushort tile[64][72];
  const int t = threadIdx.x;
  const int n0 = blockIdx.x * 64, k0 = blockIdx.y * 64;
#pragma unroll
  for (int i = 0; i < 4; ++i) {
    int p = t + i * 256;
    int r = p >> 4, c = (p & 15) << 2;
    float4 v = *reinterpret_cast<const float4*>(&W[(size_t)(k0 + r) * 3072 + n0 + c]);
    ushort4 u;
    u.x = hfbits(v.x); u.y = hfbits(v.y); u.z = hfbits(v.z); u.w = hfbits(v.w);
    *reinterpret_cast<ushort4*>(&tile[r][c]) = u;
  }
  __syncthreads();
#pragma unroll
  for (int i = 0; i < 4; ++i) {
    int p = t + i * 256;
    int rn = p >> 4, ck = (p & 15) << 2;
    ushort4 u;
    u.x = tile[ck + 0][rn]; u.y = tile[ck + 1][rn];
    u.z = tile[ck + 2][rn]; u.w = tile[ck + 3][rn];
    *reinterpret_cast<ushort4*>(&wt[(size_t)(n0 + rn) * 1024 + k0 + ck]) = u;
  }
}

// ---------------------------------------------------------------------------
// Kernel 2: qkv = x @ W  (A = x f32 [4096][1024], B = Wt fp16 [3072][1024])
// ---------------------------------------------------------------------------
__global__ __launch_bounds__(256) void k_gemm(const float* __restrict__ x,
                                              const ushort* __restrict__ wt,
                                              ushort* __restrict__ qw,
                                              ushort* __restrict__ kw,
                                              ushort* __restrict__ vw) {
  __shared__ ushort sA[128][72];
  __shared__ ushort sB[128][72];
  const int t = threadIdx.x;
  const int lane = t & 63, w = t >> 6;
  const int g = lane >> 4, lr = lane & 15;
  const int wr = w >> 1, wc = w & 1;
  const int bn = blockIdx.x, bm = blockIdx.y;

  f32x4 acc[4][4] = {};

  for (int kt = 0; kt < 1024; kt += 64) {
#pragma unroll
    for (int i = 0; i < 8; ++i) {
      int p = t + i * 256;
      int r = p >> 4, c = (p & 15) << 2;
      float4 v = *reinterpret_cast<const float4*>(
          &x[(size_t)(bm * 128 + r) * 1024 + kt + c]);
      ushort4 u;
      u.x = hfbits(v.x); u.y = hfbits(v.y); u.z = hfbits(v.z); u.w = hfbits(v.w);
      *reinterpret_cast<ushort4*>(&sA[r][c]) = u;
    }
#pragma unroll
    for (int i = 0; i < 4; ++i) {
      int p = t + i * 256;
      int r = p >> 3, c = (p & 7) << 3;
      uint4 v = *reinterpret_cast<const uint4*>(
          &wt[(size_t)(bn * 128 + r) * 1024 + kt + c]);
      *reinterpret_cast<uint4*>(&sB[r][c]) = v;
    }
    __syncthreads();
#pragma unroll
    for (int ks = 0; ks < 64; ks += 32) {
      half8 af[4], bb[4];
#pragma unroll
      for (int rs = 0; rs < 4; ++rs)
        af[rs] = *reinterpret_cast<const half8*>(&sA[wr * 64 + rs * 16 + lr][ks + g * 8]);
#pragma unroll
      for (int cs = 0; cs < 4; ++cs)
        bb[cs] = *reinterpret_cast<const half8*>(&sB[wc * 64 + cs * 16 + lr][ks + g * 8]);
#pragma unroll
      for (int rs = 0; rs < 4; ++rs)
#pragma unroll
        for (int cs = 0; cs < 4; ++cs)
          acc[rs][cs] = MFMA16(af[rs], bb[cs], acc[rs][cs]);
    }
    __syncthreads();
  }

  const int m0 = bm * 128 + wr * 64;
  const int n0 = bn * 128 + wc * 64;
  const int which = n0 >> 10;
  const int h = (n0 >> 6) & 15;
  ushort* dst = which == 0 ? qw : (which == 1 ? kw : vw);
#pragma unroll
  for (int rs = 0; rs < 4; ++rs) {
#pragma unroll
    for (int r = 0; r < 4; ++r) {
      int m = m0 + rs * 16 + g * 4 + r;
      int b = m >> 11, s = m & 2047;
      ushort* rowp = dst + ((size_t)((b << 4) + h) * 2048 + s) * 64;
#pragma unroll
      for (int cs = 0; cs < 4; ++cs)
        rowp[cs * 16 + lr] = hfbits(acc[rs][cs][r]);
    }
  }
}

// ---------------------------------------------------------------------------
// Kernel 3: v [bh][2048][64] -> vt [bh][64][2048] (fp16 transpose)
// ---------------------------------------------------------------------------
__global__ __launch_bounds__(256) void k_vt(const ushort* __restrict__ vw,
                                            ushort* __restrict__ vt) {
  __shared__ ushort tile[64][72];
  const int t = threadIdx.x;
  const int s0 = blockIdx.x * 64, bh = blockIdx.y;
#pragma unroll
  for (int i = 0; i < 2; ++i) {
    int p = t + i * 256;
    int r = p >> 3, c = (p & 7) << 3;
    uint4 v = *reinterpret_cast<const uint4*>(
        &vw[((size_t)bh * 2048 + s0 + r) * 64 + c]);
    *reinterpret_cast<uint4*>(&tile[r][c]) = v;
  }
  __syncthreads();
#pragma unroll
  for (int i = 0; i < 2; ++i) {
    int p = t + i * 256;
    int dr = p >> 3, sc = (p & 7) << 3;
    union { ushort u[8]; uint4 v; } pk;
#pragma unroll
    for (int j = 0; j < 8; ++j) pk.u[j] = tile[sc + j][dr];
    *reinterpret_cast<uint4*>(&vt[((size_t)bh * 64 + dr) * 2048 + s0 + sc]) = pk.v;
  }
}

// ---------------------------------------------------------------------------
// Kernel 4: flash attention. Was: every wave loaded the FULL K and V tile
// from global (16 KB/wave/iter -> ~320 KB/CU/iter on the L1/TA path ->
// latency/request-BW bound, MfmaUtil 5.5%). Now: block-level LDS staging
// via global_load_lds (width 16), double-buffered 2-phase schedule, XOR
// source-swizzle (involution s(r) = ((r&3)<<1)^((r>>3)&3) applied to the
// 16B column slot, same formula on the ds_read side) so both the K-read
// (rows koff+krbase) and V-read (rows dn*16+lr) patterns spread uniformly
// over all 8 slots per 128B row (2-way on banks = free).
// Math identical to previous version (verified absmax 0.03125).
// ---------------------------------------------------------------------------
__global__ __launch_bounds__(256) void k_attn(const ushort* __restrict__ qw,
                                              const ushort* __restrict__ kw,
                                              const ushort* __restrict__ vt,
                                              const int* __restrict__ mask,
                                              float* __restrict__ out) {
  __shared__ __align__(16) ushort sK[2][64][64];   // 16 KB (2 bufs)
  __shared__ __align__(16) ushort sV[2][64][64];   // 16 KB (2 bufs)

  const int t = threadIdx.x;
  const int lane = t & 63, w = t >> 6;
  const int g = lane >> 4, lr = lane & 15;
  const int qblk = blockIdx.x, bh = blockIdx.y;
  const int b = bh >> 4, h = bh & 15;

  // Q as B-operand: B col = lane&15 = q-row (within wave's 16 rows)
  const int qrow = qblk * 64 + w * 16 + lr;
  const ushort* qp = qw + ((size_t)bh * 2048 + qrow) * 64;
  const half8 qb0 = *reinterpret_cast<const half8*>(qp + g * 8);
  const half8 qb1 = *reinterpret_cast<const half8*>(qp + 32 + g * 8);

  const ushort* kbh = kw + (size_t)bh * 2048 * 64;
  const ushort* vbh = vt + (size_t)bh * 64 * 2048;
  const int* mb = mask + b * 2048;

  // permuted K row base for this lane's A-fragment row
  const int krbase = (lr >> 2) * 8 + (lr & 3);
  // read-side swizzle for K rows: s(kr) = ((lr&3)<<1) ^ (lr>>2)  (jn-invariant)
  const int kswz = (((lr & 3) << 1) ^ (lr >> 2)) << 4;

  // staging geometry: wave w stages chunks {2w, 2w+1} of both K and V tiles.
  // chunk c covers LDS bytes [c*1024, c*1024+1024): row r = c*8 + (lane>>3),
  // colbyte = (lane&7)*16. Source column is XOR-swizzled (involution).
  const int c0 = w * 2;
  const int sr0 = c0 * 8 + (lane >> 3);
  const int sr1 = sr0 + 8;
  const int scb = (lane & 7) << 4;
  const int swz0 = scb ^ (((((sr0 & 3) << 1) ^ ((sr0 >> 3) & 3))) << 4);
  const int swz1 = scb ^ (((((sr1 & 3) << 1) ^ ((sr1 >> 3) & 3))) << 4);

  auto stage = [&](int bufi, int jtn) {
    gl16(kbh + (size_t)(jtn + sr0) * 64 + (swz0 >> 1), &sK[bufi][0][0] + (c0 + 0) * 512);
    gl16(kbh + (size_t)(jtn + sr1) * 64 + (swz1 >> 1), &sK[bufi][0][0] + (c0 + 1) * 512);
    gl16(vbh + (size_t)sr0 * 2048 + jtn + (swz0 >> 1), &sV[bufi][0][0] + (c0 + 0) * 512);
    gl16(vbh + (size_t)sr1 * 2048 + jtn + (swz1 >> 1), &sV[bufi][0][0] + (c0 + 1) * 512);
  };

  float m_run = -__builtin_inff();   // running max for q = lr
  float lsum = 0.f;                  // running denom for q = lr
  f32x4 o[4] = {};                   // o[dn][r]: q = g*4+r, d = dn*16+lr

  stage(0, 0);
  __syncthreads();                   // drains vmcnt(0): tile 0 landed
  int buf = 0;

  for (int jt = 0; jt < 2048; jt += 64) {
    // ---- issue next-tile prefetch first (in flight across the whole tile)
    if (jt + 64 < 2048) stage(buf ^ 1, jt + 64);

    // ---- V fragments from LDS (independent of QK path)
    half8 vf0[4], vf1[4];
#pragma unroll
    for (int dn = 0; dn < 4; ++dn) {
      const int vr = dn * 16 + lr;
      const int vswz = ((((lr & 3) << 1) ^ ((2 * dn + (lr >> 3)) & 3)) << 4);
      const char* vrow = (const char*)&sV[buf][vr][0];
      vf0[dn] = *reinterpret_cast<const half8*>(vrow + ((16 * g) ^ vswz));
      vf1[dn] = *reinterpret_cast<const half8*>(vrow + ((64 + 16 * g) ^ vswz));
    }

    // ---- S^T via permuted-K MFMAs: st[jn][r] = S[q=lr][k=koff(jn)+g*8+r]
    float st[4][4];
#pragma unroll
    for (int jn = 0; jn < 4; ++jn) {
      const int koff = (jn & 1) * 4 + (jn >> 1) * 32;
      const int kr = koff + krbase;
      const char* krow = (const char*)&sK[buf][kr][0];
      half8 ka0 = *reinterpret_cast<const half8*>(krow + ((16 * g) ^ kswz));
      half8 ka1 = *reinterpret_cast<const half8*>(krow + ((64 + 16 * g) ^ kswz));
      f32x4 s4 = {0.f, 0.f, 0.f, 0.f};
      s4 = MFMA16(ka0, qb0, s4);
      s4 = MFMA16(ka1, qb1, s4);
      const int4 m4 = *reinterpret_cast<const int4*>(mb + jt + koff + g * 8);
      st[jn][0] = m4.x ? s4[0] : -1e9f;
      st[jn][1] = m4.y ? s4[1] : -1e9f;
      st[jn][2] = m4.z ? s4[2] : -1e9f;
      st[jn][3] = m4.w ? s4[3] : -1e9f;
    }

    // ---- row max for q=lr: 15 in-lane + 2 shfl
    float tmax = st[0][0];
#pragma unroll
    for (int jn = 0; jn < 4; ++jn)
#pragma unroll
      for (int r = 0; r < 4; ++r) tmax = fmaxf(tmax, st[jn][r]);
    tmax = fmaxf(tmax, __shfl_xor(tmax, 16));
    tmax = fmaxf(tmax, __shfl_xor(tmax, 32));

    // ---- defer-max (T13, THR=8): skip rescale when max barely grows
    if (!__all(tmax <= m_run + 8.f)) {
      const float mnew = fmaxf(m_run, tmax);
      const float sc = __expf(m_run - mnew);   // exp(-inf)=0 on first tile
      const float s0 = __shfl(sc, g * 4 + 0);
      const float s1 = __shfl(sc, g * 4 + 1);
      const float s2 = __shfl(sc, g * 4 + 2);
      const float s3 = __shfl(sc, g * 4 + 3);
#pragma unroll
      for (int dn = 0; dn < 4; ++dn) {
        o[dn][0] *= s0; o[dn][1] *= s1; o[dn][2] *= s2; o[dn][3] *= s3;
      }
      lsum *= sc;
      m_run = mnew;
    }

    // ---- P = exp(S - m): pack in-register into PV A-fragments
    float tsum = 0.f;
    unsigned int pd[8];
#pragma unroll
    for (int jn = 0; jn < 4; ++jn) {
      float p0 = __expf(st[jn][0] - m_run);
      float p1 = __expf(st[jn][1] - m_run);
      float p2 = __expf(st[jn][2] - m_run);
      float p3 = __expf(st[jn][3] - m_run);
      tsum += (p0 + p1) + (p2 + p3);
      pd[jn * 2 + 0] = __builtin_bit_cast(unsigned int, __builtin_amdgcn_cvt_pkrtz(p0, p1));
      pd[jn * 2 + 1] = __builtin_bit_cast(unsigned int, __builtin_amdgcn_cvt_pkrtz(p2, p3));
    }
    tsum += __shfl_xor(tsum, 16);
    tsum += __shfl_xor(tsum, 32);
    lsum += tsum;

    union { unsigned int u[4]; half8 h; } pa0u, pa1u;
    pa0u.u[0] = pd[0]; pa0u.u[1] = pd[1]; pa0u.u[2] = pd[2]; pa0u.u[3] = pd[3];
    pa1u.u[0] = pd[4]; pa1u.u[1] = pd[5]; pa1u.u[2] = pd[6]; pa1u.u[3] = pd[7];

    __builtin_amdgcn_s_setprio(1);
#pragma unroll
    for (int dn = 0; dn < 4; ++dn) {
      o[dn] = MFMA16(pa0u.h, vf0[dn], o[dn]);
      o[dn] = MFMA16(pa1u.h, vf1[dn], o[dn]);
    }
    __builtin_amdgcn_s_setprio(0);

    // one barrier per tile: __syncthreads drains vmcnt(0) (prefetch landed)
    // and guarantees all waves done reading buf before it is overwritten.
    __syncthreads();
    buf ^= 1;
  }

  // ---- epilogue: redistribute 1/lsum (held at q=lr) to o-layout (q=g*4+r)
  const float rinv = 1.f / lsum;
  const float i0 = __shfl(rinv, g * 4 + 0);
  const float i1 = __shfl(rinv, g * 4 + 1);
  const float i2 = __shfl(rinv, g * 4 + 2);
  const float i3 = __shfl(rinv, g * 4 + 3);
  const int s0r = qblk * 64 + w * 16 + g * 4;
  float* ob = out + ((size_t)b * 2048 + s0r) * 1024 + h * 64;
#pragma unroll
  for (int dn = 0; dn < 4; ++dn) {
    ob[0 * 1024 + dn * 16 + lr] = o[dn][0] * i0;
    ob[1 * 1024 + dn * 16 + lr] = o[dn][1] * i1;
    ob[2 * 1024 + dn * 16 + lr] = o[dn][2] * i2;
    ob[3 * 1024 + dn * 16 + lr] = o[dn][3] * i3;
  }
}

// ---------------------------------------------------------------------------
extern "C" void kernel_launch(void* const* d_in, const int* in_sizes, int n_in,
                              void* d_out, int out_size, void* d_ws, size_t ws_size,
                              hipStream_t stream) {
  const float* x = (const float*)d_in[0];     // [2][2048][1024] f32
  const float* W = (const float*)d_in[1];     // [1024][3072] f32
  const int* mask = (const int*)d_in[2];      // [2][2048] i32
  float* out = (float*)d_out;                 // [2][2048][1024] f32
  char* ws = (char*)d_ws;

  ushort* wt = (ushort*)(ws);                                  // 6,291,456 B
  ushort* qw = (ushort*)(ws + 6291456);                        // 8,388,608 B
  ushort* kw = (ushort*)(ws + 6291456 + 8388608);              // 8,388,608 B
  ushort* vw = (ushort*)(ws + 6291456 + 2 * 8388608);          // 8,388,608 B
  ushort* vt = (ushort*)(ws + 6291456 + 3 * (size_t)8388608);  // 8,388,608 B

  k_wt<<<dim3(48, 16), 256, 0, stream>>>(W, wt);
  k_gemm<<<dim3(24, 32), 256, 0, stream>>>(x, wt, qw, kw, vw);
  k_vt<<<dim3(32, 32), 256, 0, stream>>>(vw, vt);
  k_attn<<<dim3(32, 32), 256, 0, stream>>>(qw, kw, vt, mask, out);
}

// Round 2
// 123.842 us; speedup vs baseline: 2.4692x; 1.2587x over previous
//
#include <hip/hip_runtime.h>

typedef _Float16 half8 __attribute__((ext_vector_type(8)));
typedef float f32x4 __attribute__((ext_vector_type(4)));

#define MFMA16(a, b, c) __builtin_amdgcn_mfma_f32_16x16x32_f16((a), (b), (c), 0, 0, 0)

static __device__ __forceinline__ unsigned short hfbits(float f) {
  return __builtin_bit_cast(unsigned short, (_Float16)f);
}

// async global->LDS, 16B per lane; LDS dest = uniform base + lane*16
static __device__ __forceinline__ void gl16(const ushort* g, ushort* l) {
  __builtin_amdgcn_global_load_lds(
      (const __attribute__((address_space(1))) unsigned int*)g,
      (__attribute__((address_space(3))) unsigned int*)l, 16, 0, 0);
}

// ---------------------------------------------------------------------------
// Kernel 1: W [1024][3072] f32  ->  Wt [3072][1024] fp16 (transposed + cast)
// ---------------------------------------------------------------------------
__global__ __launch_bounds__(256) void k_wt(const float* __restrict__ W,
                                            ushort* __restrict__ wt) {
  __shared__ ushort tile[64][72];
  const int t = threadIdx.x;
  const int n0 = blockIdx.x * 64, k0 = blockIdx.y * 64;
#pragma unroll
  for (int i = 0; i < 4; ++i) {
    int p = t + i * 256;
    int r = p >> 4, c = (p & 15) << 2;
    float4 v = *reinterpret_cast<const float4*>(&W[(size_t)(k0 + r) * 3072 + n0 + c]);
    ushort4 u;
    u.x = hfbits(v.x); u.y = hfbits(v.y); u.z = hfbits(v.z); u.w = hfbits(v.w);
    *reinterpret_cast<ushort4*>(&tile[r][c]) = u;
  }
  __syncthreads();
#pragma unroll
  for (int i = 0; i < 4; ++i) {
    int p = t + i * 256;
    int rn = p >> 4, ck = (p & 15) << 2;
    ushort4 u;
    u.x = tile[ck + 0][rn]; u.y = tile[ck + 1][rn];
    u.z = tile[ck + 2][rn]; u.w = tile[ck + 3][rn];
    *reinterpret_cast<ushort4*>(&wt[(size_t)(n0 + rn) * 1024 + k0 + ck]) = u;
  }
}

// ---------------------------------------------------------------------------
// Kernel 2: qkv = x @ W.  Q outputs are pre-scaled by log2(e) so k_attn can
// use v_exp_f32 (exp2) directly with no per-element mul (single-rounding:
// scale applied in f32 before the one f32->f16 round).
// ---------------------------------------------------------------------------
__global__ __launch_bounds__(256) void k_gemm(const float* __restrict__ x,
                                              const ushort* __restrict__ wt,
                                              ushort* __restrict__ qw,
                                              ushort* __restrict__ kw,
                                              ushort* __restrict__ vw) {
  __shared__ ushort sA[128][72];
  __shared__ ushort sB[128][72];
  const int t = threadIdx.x;
  const int lane = t & 63, w = t >> 6;
  const int g = lane >> 4, lr = lane & 15;
  const int wr = w >> 1, wc = w & 1;
  const int bn = blockIdx.x, bm = blockIdx.y;

  f32x4 acc[4][4] = {};

  for (int kt = 0; kt < 1024; kt += 64) {
#pragma unroll
    for (int i = 0; i < 8; ++i) {
      int p = t + i * 256;
      int r = p >> 4, c = (p & 15) << 2;
      float4 v = *reinterpret_cast<const float4*>(
          &x[(size_t)(bm * 128 + r) * 1024 + kt + c]);
      ushort4 u;
      u.x = hfbits(v.x); u.y = hfbits(v.y); u.z = hfbits(v.z); u.w = hfbits(v.w);
      *reinterpret_cast<ushort4*>(&sA[r][c]) = u;
    }
#pragma unroll
    for (int i = 0; i < 4; ++i) {
      int p = t + i * 256;
      int r = p >> 3, c = (p & 7) << 3;
      uint4 v = *reinterpret_cast<const uint4*>(
          &wt[(size_t)(bn * 128 + r) * 1024 + kt + c]);
      *reinterpret_cast<uint4*>(&sB[r][c]) = v;
    }
    __syncthreads();
#pragma unroll
    for (int ks = 0; ks < 64; ks += 32) {
      half8 af[4], bb[4];
#pragma unroll
      for (int rs = 0; rs < 4; ++rs)
        af[rs] = *reinterpret_cast<const half8*>(&sA[wr * 64 + rs * 16 + lr][ks + g * 8]);
#pragma unroll
      for (int cs = 0; cs < 4; ++cs)
        bb[cs] = *reinterpret_cast<const half8*>(&sB[wc * 64 + cs * 16 + lr][ks + g * 8]);
#pragma unroll
      for (int rs = 0; rs < 4; ++rs)
#pragma unroll
        for (int cs = 0; cs < 4; ++cs)
          acc[rs][cs] = MFMA16(af[rs], bb[cs], acc[rs][cs]);
    }
    __syncthreads();
  }

  const int m0 = bm * 128 + wr * 64;
  const int n0 = bn * 128 + wc * 64;
  const int which = n0 >> 10;
  const int h = (n0 >> 6) & 15;
  ushort* dst = which == 0 ? qw : (which == 1 ? kw : vw);
  const float qsc = which == 0 ? 1.44269504088896f : 1.0f;  // log2(e) for Q
#pragma unroll
  for (int rs = 0; rs < 4; ++rs) {
#pragma unroll
    for (int r = 0; r < 4; ++r) {
      int m = m0 + rs * 16 + g * 4 + r;
      int b = m >> 11, s = m & 2047;
      ushort* rowp = dst + ((size_t)((b << 4) + h) * 2048 + s) * 64;
#pragma unroll
      for (int cs = 0; cs < 4; ++cs)
        rowp[cs * 16 + lr] = hfbits(acc[rs][cs][r] * qsc);
    }
  }
}

// ---------------------------------------------------------------------------
// Kernel 3: v [bh][2048][64] -> vt [bh][64][2048] (fp16 transpose)
// ---------------------------------------------------------------------------
__global__ __launch_bounds__(256) void k_vt(const ushort* __restrict__ vw,
                                            ushort* __restrict__ vt) {
  __shared__ ushort tile[64][72];
  const int t = threadIdx.x;
  const int s0 = blockIdx.x * 64, bh = blockIdx.y;
#pragma unroll
  for (int i = 0; i < 2; ++i) {
    int p = t + i * 256;
    int r = p >> 3, c = (p & 7) << 3;
    uint4 v = *reinterpret_cast<const uint4*>(
        &vw[((size_t)bh * 2048 + s0 + r) * 64 + c]);
    *reinterpret_cast<uint4*>(&tile[r][c]) = v;
  }
  __syncthreads();
#pragma unroll
  for (int i = 0; i < 2; ++i) {
    int p = t + i * 256;
    int dr = p >> 3, sc = (p & 7) << 3;
    union { ushort u[8]; uint4 v; } pk;
#pragma unroll
    for (int j = 0; j < 8; ++j) pk.u[j] = tile[sc + j][dr];
    *reinterpret_cast<uint4*>(&vt[((size_t)bh * 64 + dr) * 2048 + s0 + sc]) = pk.v;
  }
}

// ---------------------------------------------------------------------------
// Kernel 4: flash attention, 8 waves / 512 threads per block.
// Round-1 counters showed OccupancyPercent 24% (2 blocks/CU with 32KB LDS)
// -> only 8 waves/CU hiding latency. Merging two 4-wave blocks into one
// 8-wave block (128 q-rows) keeps LDS at 32KB but restores 16 waves/CU,
// and halves per-CU staging traffic (one block stages K+V for 8 waves).
// exp path: Q is pre-scaled by log2e in k_gemm -> S is in log2 units ->
// v_exp_f32 (exp2) directly; running max / defer-max operate in log2 units.
// ---------------------------------------------------------------------------
__global__ __launch_bounds__(512) void k_attn(const ushort* __restrict__ qw,
                                              const ushort* __restrict__ kw,
                                              const ushort* __restrict__ vt,
                                              const int* __restrict__ mask,
                                              float* __restrict__ out) {
  __shared__ __align__(16) ushort sK[2][64][64];   // 16 KB (2 bufs)
  __shared__ __align__(16) ushort sV[2][64][64];   // 16 KB (2 bufs)

  const int t = threadIdx.x;
  const int lane = t & 63, w = t >> 6;             // w in 0..7
  const int g = lane >> 4, lr = lane & 15;
  const int qblk = blockIdx.x, bh = blockIdx.y;
  const int b = bh >> 4, h = bh & 15;

  // Q as B-operand: B col = lane&15 = q-row (within wave's 16 rows)
  const int qrow = qblk * 128 + w * 16 + lr;
  const ushort* qp = qw + ((size_t)bh * 2048 + qrow) * 64;
  const half8 qb0 = *reinterpret_cast<const half8*>(qp + g * 8);
  const half8 qb1 = *reinterpret_cast<const half8*>(qp + 32 + g * 8);

  const ushort* kbh = kw + (size_t)bh * 2048 * 64;
  const ushort* vbh = vt + (size_t)bh * 64 * 2048;
  const int* mb = mask + b * 2048;

  // permuted K row base for this lane's A-fragment row
  const int krbase = (lr >> 2) * 8 + (lr & 3);
  // read-side swizzle for K rows: s(kr) = ((lr&3)<<1) ^ (lr>>2)  (jn-invariant)
  const int kswz = (((lr & 3) << 1) ^ (lr >> 2)) << 4;

  // staging geometry: wave w stages chunk w (1 KB) of both K and V tiles.
  // chunk w covers rows w*8 + (lane>>3), colbyte (lane&7)*16, source column
  // XOR-swizzled with the involution s(r) = ((r&3)<<1) ^ ((r>>3)&3).
  const int sr0 = w * 8 + (lane >> 3);
  const int scb = (lane & 7) << 4;
  const int swz0 = scb ^ ((((sr0 & 3) << 1) ^ ((sr0 >> 3) & 3)) << 4);

  auto stage = [&](int bufi, int jtn) {
    gl16(kbh + (size_t)(jtn + sr0) * 64 + (swz0 >> 1), &sK[bufi][0][0] + w * 512);
    gl16(vbh + (size_t)sr0 * 2048 + jtn + (swz0 >> 1), &sV[bufi][0][0] + w * 512);
  };

  float m_run = -__builtin_inff();   // running max (log2 units) for q = lr
  float lsum = 0.f;                  // running denom for q = lr
  f32x4 o[4] = {};                   // o[dn][r]: q = g*4+r, d = dn*16+lr

  stage(0, 0);
  __syncthreads();                   // drains vmcnt(0): tile 0 landed
  int buf = 0;

  for (int jt = 0; jt < 2048; jt += 64) {
    // ---- issue next-tile prefetch first (in flight across the whole tile)
    if (jt + 64 < 2048) stage(buf ^ 1, jt + 64);

    // ---- V fragments from LDS (independent of QK path)
    half8 vf0[4], vf1[4];
#pragma unroll
    for (int dn = 0; dn < 4; ++dn) {
      const int vr = dn * 16 + lr;
      const int vswz = ((((lr & 3) << 1) ^ ((2 * dn + (lr >> 3)) & 3)) << 4);
      const char* vrow = (const char*)&sV[buf][vr][0];
      vf0[dn] = *reinterpret_cast<const half8*>(vrow + ((16 * g) ^ vswz));
      vf1[dn] = *reinterpret_cast<const half8*>(vrow + ((64 + 16 * g) ^ vswz));
    }

    // ---- S^T via permuted-K MFMAs: st[jn][r] = S[q=lr][k=koff(jn)+g*8+r]
    float st[4][4];
#pragma unroll
    for (int jn = 0; jn < 4; ++jn) {
      const int koff = (jn & 1) * 4 + (jn >> 1) * 32;
      const int kr = koff + krbase;
      const char* krow = (const char*)&sK[buf][kr][0];
      half8 ka0 = *reinterpret_cast<const half8*>(krow + ((16 * g) ^ kswz));
      half8 ka1 = *reinterpret_cast<const half8*>(krow + ((64 + 16 * g) ^ kswz));
      f32x4 s4 = {0.f, 0.f, 0.f, 0.f};
      s4 = MFMA16(ka0, qb0, s4);
      s4 = MFMA16(ka1, qb1, s4);
      const int4 m4 = *reinterpret_cast<const int4*>(mb + jt + koff + g * 8);
      st[jn][0] = m4.x ? s4[0] : -1e9f;
      st[jn][1] = m4.y ? s4[1] : -1e9f;
      st[jn][2] = m4.z ? s4[2] : -1e9f;
      st[jn][3] = m4.w ? s4[3] : -1e9f;
    }

    // ---- row max for q=lr: 15 in-lane + 2 shfl
    float tmax = st[0][0];
#pragma unroll
    for (int jn = 0; jn < 4; ++jn)
#pragma unroll
      for (int r = 0; r < 4; ++r) tmax = fmaxf(tmax, st[jn][r]);
    tmax = fmaxf(tmax, __shfl_xor(tmax, 16));
    tmax = fmaxf(tmax, __shfl_xor(tmax, 32));

    // ---- defer-max (T13): skip rescale when max barely grows (log2 units)
    if (!__all(tmax <= m_run + 8.f)) {
      const float mnew = fmaxf(m_run, tmax);
      const float sc = __builtin_amdgcn_exp2f(m_run - mnew);  // exp2(-inf)=0
      const float s0 = __shfl(sc, g * 4 + 0);
      const float s1 = __shfl(sc, g * 4 + 1);
      const float s2 = __shfl(sc, g * 4 + 2);
      const float s3 = __shfl(sc, g * 4 + 3);
#pragma unroll
      for (int dn = 0; dn < 4; ++dn) {
        o[dn][0] *= s0; o[dn][1] *= s1; o[dn][2] *= s2; o[dn][3] *= s3;
      }
      lsum *= sc;
      m_run = mnew;
    }

    // ---- P = exp2(S2 - m2): pack in-register into PV A-fragments
    float tsum = 0.f;
    unsigned int pd[8];
#pragma unroll
    for (int jn = 0; jn < 4; ++jn) {
      float p0 = __builtin_amdgcn_exp2f(st[jn][0] - m_run);
      float p1 = __builtin_amdgcn_exp2f(st[jn][1] - m_run);
      float p2 = __builtin_amdgcn_exp2f(st[jn][2] - m_run);
      float p3 = __builtin_amdgcn_exp2f(st[jn][3] - m_run);
      tsum += (p0 + p1) + (p2 + p3);
      pd[jn * 2 + 0] = __builtin_bit_cast(unsigned int, __builtin_amdgcn_cvt_pkrtz(p0, p1));
      pd[jn * 2 + 1] = __builtin_bit_cast(unsigned int, __builtin_amdgcn_cvt_pkrtz(p2, p3));
    }
    tsum += __shfl_xor(tsum, 16);
    tsum += __shfl_xor(tsum, 32);
    lsum += tsum;

    union { unsigned int u[4]; half8 h; } pa0u, pa1u;
    pa0u.u[0] = pd[0]; pa0u.u[1] = pd[1]; pa0u.u[2] = pd[2]; pa0u.u[3] = pd[3];
    pa1u.u[0] = pd[4]; pa1u.u[1] = pd[5]; pa1u.u[2] = pd[6]; pa1u.u[3] = pd[7];

    __builtin_amdgcn_s_setprio(1);
#pragma unroll
    for (int dn = 0; dn < 4; ++dn) {
      o[dn] = MFMA16(pa0u.h, vf0[dn], o[dn]);
      o[dn] = MFMA16(pa1u.h, vf1[dn], o[dn]);
    }
    __builtin_amdgcn_s_setprio(0);

    // one barrier per tile: drains vmcnt(0) (prefetch landed) and protects buf
    __syncthreads();
    buf ^= 1;
  }

  // ---- epilogue: redistribute 1/lsum (held at q=lr) to o-layout (q=g*4+r)
  const float rinv = 1.f / lsum;
  const float i0 = __shfl(rinv, g * 4 + 0);
  const float i1 = __shfl(rinv, g * 4 + 1);
  const float i2 = __shfl(rinv, g * 4 + 2);
  const float i3 = __shfl(rinv, g * 4 + 3);
  const int s0r = qblk * 128 + w * 16 + g * 4;
  float* ob = out + ((size_t)b * 2048 + s0r) * 1024 + h * 64;
#pragma unroll
  for (int dn = 0; dn < 4; ++dn) {
    ob[0 * 1024 + dn * 16 + lr] = o[dn][0] * i0;
    ob[1 * 1024 + dn * 16 + lr] = o[dn][1] * i1;
    ob[2 * 1024 + dn * 16 + lr] = o[dn][2] * i2;
    ob[3 * 1024 + dn * 16 + lr] = o[dn][3] * i3;
  }
}

// ---------------------------------------------------------------------------
extern "C" void kernel_launch(void* const* d_in, const int* in_sizes, int n_in,
                              void* d_out, int out_size, void* d_ws, size_t ws_size,
                              hipStream_t stream) {
  const float* x = (const float*)d_in[0];     // [2][2048][1024] f32
  const float* W = (const float*)d_in[1];     // [1024][3072] f32
  const int* mask = (const int*)d_in[2];      // [2][2048] i32
  float* out = (float*)d_out;                 // [2][2048][1024] f32
  char* ws = (char*)d_ws;

  ushort* wt = (ushort*)(ws);                                  // 6,291,456 B
  ushort* qw = (ushort*)(ws + 6291456);                        // 8,388,608 B
  ushort* kw = (ushort*)(ws + 6291456 + 8388608);              // 8,388,608 B
  ushort* vw = (ushort*)(ws + 6291456 + 2 * 8388608);          // 8,388,608 B
  ushort* vt = (ushort*)(ws + 6291456 + 3 * (size_t)8388608);  // 8,388,608 B

  k_wt<<<dim3(48, 16), 256, 0, stream>>>(W, wt);
  k_gemm<<<dim3(24, 32), 256, 0, stream>>>(x, wt, qw, kw, vw);
  k_vt<<<dim3(32, 32), 256, 0, stream>>>(vw, vt);
  k_attn<<<dim3(16, 32), 512, 0, stream>>>(qw, kw, vt, mask, out);
}